// Round 17
// baseline (1991.288 us; speedup 1.0000x reference)
//
#include <hip/hip_runtime.h>
#include <hip/hip_fp16.h>

#define T_LEN 4096
#define BATCH 256
#define HID   25
#define G4    100
#define NSEG  16
#define SEG_T (T_LEN / NSEG)   // 256
#define TG    32
#define NTG   (SEG_T / TG)     // 8

#define LOG2E  1.4426950408889634f
#define LOG2E2 2.8853900817779268f

#define DEV __device__ __forceinline__

#define REP13(M) M(0) M(1) M(2) M(3) M(4) M(5) M(6) M(7) M(8) M(9) M(10) M(11) M(12)

DEV float rcpf_(float x){
#if __has_builtin(__builtin_amdgcn_rcpf)
    return __builtin_amdgcn_rcpf(x);
#else
    return 1.0f / x;
#endif
}
DEV float readlane_f(float v, int j){
#if __has_builtin(__builtin_amdgcn_readlane)
    return __int_as_float(__builtin_amdgcn_readlane(__float_as_int(v), j));
#else
    return __shfl(v, j);
#endif
}
DEV unsigned pkrtz_(float a, float b){
#if __has_builtin(__builtin_amdgcn_cvt_pkrtz)
    return __builtin_bit_cast(unsigned, __builtin_amdgcn_cvt_pkrtz(a, b));
#else
    __half2 h = __floats2half2_rn(a, b);
    return __builtin_bit_cast(unsigned, h);
#endif
}
DEV float dot2acc(unsigned w, unsigned xv, float acc){
#if __has_builtin(__builtin_amdgcn_fdot2)
    typedef _Float16 h2v __attribute__((ext_vector_type(2)));
    return __builtin_amdgcn_fdot2(__builtin_bit_cast(h2v, w),
                                  __builtin_bit_cast(h2v, xv), acc, false);
#else
    __half2 a = __builtin_bit_cast(__half2, w), b2 = __builtin_bit_cast(__half2, xv);
    float2 fa = __half22float2(a), fb = __half22float2(b2);
    return acc + fa.x * fb.x + fa.y * fb.y;
#endif
}
DEV float sigm_(float x){ return 1.0f - rcpf_(__expf(x) + 1.0f); }
DEV float tanhx_(float x){ return 1.0f - 2.0f * rcpf_(__expf(2.0f * x) + 1.0f); }

// row0-broadcast: every lane receives the value held by lane (lane&31) of the LOWER half.
// Verified on HW (rounds 4-16, absmax 0).
DEV float bcast_row0(float v){
#if __has_builtin(__builtin_amdgcn_permlane32_swap)
    auto r = __builtin_amdgcn_permlane32_swap(__float_as_int(v), __float_as_int(v), false, false);
    return __int_as_float(r[0]);
#else
    return __shfl(v, (int)(threadIdx.x & 31), 64);
#endif
}

// ============ recurrence: R7-EXACT chain (334 ns/step measured, round 7) ============
// Weights computed INLINE from w_hh (float load + scale + pkrtz, 26 packed dwords) and
// RE-PINNED via empty asm volatile at the top of EVERY 8-step block — this is the one
// feature present in every 334 ns/step measurement and absent from every ~500 ns/step one.
// lane k (<32): gates (i,f); lane 32+k: gates (g,o). Cell update lane-local on upper half.
template<bool STORE>
DEV void rec_block(const __half* __restrict__ xg,
                   const float* __restrict__ w_hh,
                   __half* __restrict__ h0out,
                   float* __restrict__ stH, float* __restrict__ stC,
                   int b, int dir, int seg, int first)
{
    const int lane = threadIdx.x;          // caller guarantees < 64
    const int k    = ((lane & 31) < HID) ? (lane & 31) : 0;
    const bool up  = lane >= 32;
    const int rowA = up ? (2 * HID + k) : k;          // g : i
    const int rowB = up ? (3 * HID + k) : (HID + k);  // o : f
    const float scA  = up ? LOG2E2 : LOG2E;
    const float coef = up ? 2.0f : 1.0f;

#define DECLW(m) unsigned wA##m, wB##m;
    REP13(DECLW)
#undef DECLW
#define LOADW(m) { \
    const bool tl = (2 * m + 1 < HID); \
    float a0 = w_hh[rowA * HID + 2 * m] * scA; \
    float a1 = tl ? w_hh[rowA * HID + 2 * m + 1] * scA : 0.0f; \
    float b0 = w_hh[rowB * HID + 2 * m] * LOG2E; \
    float b1 = tl ? w_hh[rowB * HID + 2 * m + 1] * LOG2E : 0.0f; \
    wA##m = pkrtz_(a0, a1); \
    wB##m = pkrtz_(b0, b1); }
    REP13(LOADW)
#undef LOADW

    const int sidx = (dir * BATCH + b) * 32 + k;
    float h = 0.0f, cst = 0.0f;
    if (!first) { h = stH[sidx]; cst = stC[sidx]; }

    const unsigned* src = (const unsigned*)xg + (size_t)b * SEG_T * (G4 / 2)
                        + (k * 2 + (up ? 1 : 0));
    unsigned pf[8];
    #pragma unroll
    for (int s = 0; s < 8; ++s) pf[s] = src[s * (G4 / 2)];
    const unsigned* pnext = src + 8 * (G4 / 2);

    __half* sptr = nullptr;
    long long sstride = 0;
    if (STORE) {
        const int tstart = dir ? (seg * SEG_T + SEG_T - 1) : (seg * SEG_T);
        sptr = h0out + ((size_t)b * T_LEN + tstart) * (2 * HID) + dir * HID + k;
        sstride = dir ? -(long long)(2 * HID) : (long long)(2 * HID);
    }
    const bool store_lane = up && ((lane & 31) < HID);

    for (int tb = 0; tb < SEG_T; tb += 8) {
        // pin the 26 packed weights live across the back-edge (R7's critical ingredient)
        asm volatile("" :
            "+v"(wA0), "+v"(wA1), "+v"(wA2), "+v"(wA3), "+v"(wA4), "+v"(wA5),
            "+v"(wA6), "+v"(wA7), "+v"(wA8), "+v"(wA9), "+v"(wA10), "+v"(wA11), "+v"(wA12),
            "+v"(wB0), "+v"(wB1), "+v"(wB2), "+v"(wB3), "+v"(wB4), "+v"(wB5),
            "+v"(wB6), "+v"(wB7), "+v"(wB8), "+v"(wB9), "+v"(wB10), "+v"(wB11), "+v"(wB12));
        #pragma unroll
        for (int s = 0; s < 8; ++s) {
            const unsigned cur = pf[s];
            pf[s] = pnext[s * (G4 / 2)];             // rolling prefetch t+8 (pad absorbs tail)
            const __half2 hx = __builtin_bit_cast(__half2, cur);
            const float2 xv = __half22float2(hx);
#define HP(m) unsigned hp##m; { float ha_ = readlane_f(h, 32 + 2*m); \
            float hb_ = (2*m+1 < HID) ? readlane_f(h, 32 + 2*m + 1) : 0.0f; \
            hp##m = pkrtz_(ha_, hb_); }
            REP13(HP)
#undef HP
            float aA0 = xv.x, aA1 = 0.0f, aB0 = xv.y, aB1 = 0.0f;
#define DT(m) { if ((m) & 1) { aA1 = dot2acc(wA##m, hp##m, aA1); aB1 = dot2acc(wB##m, hp##m, aB1); } \
                else         { aA0 = dot2acc(wA##m, hp##m, aA0); aB0 = dot2acc(wB##m, hp##m, aB0); } }
            REP13(DT)
#undef DT
            const float aA = aA0 + aA1;
            const float aB = aB0 + aB1;
            float e0 = __builtin_exp2f(aA);
            float e1 = __builtin_exp2f(aB);
            float u0 = 1.0f - coef * rcpf_(e0 + 1.0f);   // lower: sig(i); upper: tanh(g)
            float u1 = 1.0f - rcpf_(e1 + 1.0f);          // lower: sig(f); upper: sig(o)
            float si = bcast_row0(u0);
            float sf = bcast_row0(u1);
            cst = sf * cst + si * u0;                    // upper: f*c + i*tanh(g)
            float tc = 1.0f - 2.0f * rcpf_(__builtin_exp2f(LOG2E2 * cst) + 1.0f);
            h = u1 * tc;                                 // upper: sig(o)*tanh(c)
            if (STORE) {
                if (store_lane) *sptr = __float2half(h);
                sptr += sstride;
            }
        }
        pnext += 8 * (G4 / 2);
    }
    if (store_lane) { stH[sidx] = h; stC[sidx] = cst; }
}

// ================= xg GEMM blocks =================
#define OG_U4 ((TG * G4) / 8)   // 400 uint4 (R12/R13 bug was TG*(G4/8)=384)

// l0: f32 math, f32 LDS rows padded to 28 -> 6 x ds_read_b128 + 1 b32 per t.
DEV void gemm_l0_block(float* xs, __half* og,
                       const float* __restrict__ x,
                       const float* __restrict__ w_ih, const float* __restrict__ b_ih,
                       const float* __restrict__ b_hh,
                       __half* __restrict__ xgdst, int b, int by, int dir, int seg)
{
    const int tid = threadIdx.x;
    const int t0 = seg * SEG_T + by * TG;
    const float* src = x + ((size_t)b * T_LEN + t0) * HID;
    #pragma unroll
    for (int i = 0; i < 7; ++i) {
        int idx = tid + 128 * i;
        if (idx < TG * HID) {
            int r = idx / HID, d = idx - r * HID;
            int row = dir ? (TG - 1 - r) : r;
            xs[row * 28 + d] = src[idx];
        }
    }
    __syncthreads();
    if (tid < G4) {
        const int g = tid;
        const float sc = (g >= 2 * HID && g < 3 * HID) ? LOG2E2 : LOG2E;
        float w[HID];
        #pragma unroll
        for (int j = 0; j < HID; ++j) w[j] = w_ih[g * HID + j] * sc;
        const float bias = (b_ih[g] + b_hh[g]) * sc;
        const int pos = (g % HID) * 4 + (g / HID);
        for (int t = 0; t < TG; ++t) {
            const float4* xq = (const float4*)(xs + t * 28);
            float4 q0 = xq[0], q1 = xq[1], q2 = xq[2], q3 = xq[3], q4 = xq[4], q5 = xq[5];
            float e24 = xs[t * 28 + 24];
            float a0 = bias, a1 = 0.f, a2 = 0.f, a3 = 0.f;
            a0 = fmaf(w[0],  q0.x, a0);  a1 = fmaf(w[1],  q0.y, a1);
            a2 = fmaf(w[2],  q0.z, a2);  a3 = fmaf(w[3],  q0.w, a3);
            a0 = fmaf(w[4],  q1.x, a0);  a1 = fmaf(w[5],  q1.y, a1);
            a2 = fmaf(w[6],  q1.z, a2);  a3 = fmaf(w[7],  q1.w, a3);
            a0 = fmaf(w[8],  q2.x, a0);  a1 = fmaf(w[9],  q2.y, a1);
            a2 = fmaf(w[10], q2.z, a2);  a3 = fmaf(w[11], q2.w, a3);
            a0 = fmaf(w[12], q3.x, a0);  a1 = fmaf(w[13], q3.y, a1);
            a2 = fmaf(w[14], q3.z, a2);  a3 = fmaf(w[15], q3.w, a3);
            a0 = fmaf(w[16], q4.x, a0);  a1 = fmaf(w[17], q4.y, a1);
            a2 = fmaf(w[18], q4.z, a2);  a3 = fmaf(w[19], q4.w, a3);
            a0 = fmaf(w[20], q5.x, a0);  a1 = fmaf(w[21], q5.y, a1);
            a2 = fmaf(w[22], q5.z, a2);  a3 = fmaf(w[23], q5.w, a3);
            a0 = fmaf(w[24], e24, a0);
            og[t * G4 + pos] = __float2half((a0 + a1) + (a2 + a3));
        }
    }
    __syncthreads();
    const int rowbase = (dir ? (NTG - 1 - by) : by) * TG;
    uint4* dstq = (uint4*)((unsigned*)xgdst + ((size_t)b * SEG_T + rowbase) * (G4 / 2));
    const uint4* ogq = (const uint4*)og;
    #pragma unroll
    for (int i = 0; i < 4; ++i) { int idx = tid + 128 * i; if (idx < OG_U4) dstq[idx] = ogq[idx]; }
}

// l1: fp16 inputs (h0 already fp16); rows padded to 28 dwords; RNE weight packing (R11-validated).
DEV void gemm_l1_block(unsigned* xs, __half* og,
                       const __half* __restrict__ h0,
                       const float* __restrict__ w_ih, const float* __restrict__ b_ih,
                       const float* __restrict__ b_hh,
                       __half* __restrict__ xgdst, int b, int by, int seg)
{
    const int tid = threadIdx.x;
    const int t0 = seg * SEG_T + by * TG;
    const unsigned* src = (const unsigned*)h0 + ((size_t)b * T_LEN + t0) * HID;
    #pragma unroll
    for (int i = 0; i < 7; ++i) {
        int idx = tid + 128 * i;
        if (idx < TG * HID) {
            int r = idx / HID, d = idx - r * HID;
            xs[r * 28 + d] = src[idx];
        }
    }
    __syncthreads();
    if (tid < G4) {
        const int g = tid;
        const float sc = (g >= 2 * HID && g < 3 * HID) ? LOG2E2 : LOG2E;
        unsigned wp[HID];
        #pragma unroll
        for (int j = 0; j < HID; ++j) {
            __half2 hw = __floats2half2_rn(w_ih[g * (2 * HID) + 2 * j] * sc,
                                           w_ih[g * (2 * HID) + 2 * j + 1] * sc);
            wp[j] = __builtin_bit_cast(unsigned, hw);
        }
        const float bias = (b_ih[g] + b_hh[g]) * sc;
        const int pos = (g % HID) * 4 + (g / HID);
        for (int t = 0; t < TG; ++t) {
            const uint4* xq = (const uint4*)(xs + t * 28);
            uint4 q0 = xq[0], q1 = xq[1], q2 = xq[2], q3 = xq[3], q4 = xq[4], q5 = xq[5];
            unsigned d24 = xs[t * 28 + 24];
            float a0 = bias, a1 = 0.f, a2 = 0.f, a3 = 0.f;
            a0 = dot2acc(wp[0], q0.x, a0);   a1 = dot2acc(wp[1], q0.y, a1);
            a2 = dot2acc(wp[2], q0.z, a2);   a3 = dot2acc(wp[3], q0.w, a3);
            a0 = dot2acc(wp[4], q1.x, a0);   a1 = dot2acc(wp[5], q1.y, a1);
            a2 = dot2acc(wp[6], q1.z, a2);   a3 = dot2acc(wp[7], q1.w, a3);
            a0 = dot2acc(wp[8], q2.x, a0);   a1 = dot2acc(wp[9], q2.y, a1);
            a2 = dot2acc(wp[10], q2.z, a2);  a3 = dot2acc(wp[11], q2.w, a3);
            a0 = dot2acc(wp[12], q3.x, a0);  a1 = dot2acc(wp[13], q3.y, a1);
            a2 = dot2acc(wp[14], q3.z, a2);  a3 = dot2acc(wp[15], q3.w, a3);
            a0 = dot2acc(wp[16], q4.x, a0);  a1 = dot2acc(wp[17], q4.y, a1);
            a2 = dot2acc(wp[18], q4.z, a2);  a3 = dot2acc(wp[19], q4.w, a3);
            a0 = dot2acc(wp[20], q5.x, a0);  a1 = dot2acc(wp[21], q5.y, a1);
            a2 = dot2acc(wp[22], q5.z, a2);  a3 = dot2acc(wp[23], q5.w, a3);
            a0 = dot2acc(wp[24], d24, a0);
            og[t * G4 + pos] = __float2half((a0 + a1) + (a2 + a3));
        }
    }
    __syncthreads();
    uint4* dstq = (uint4*)((unsigned*)xgdst + ((size_t)b * SEG_T + (size_t)by * TG) * (G4 / 2));
    const uint4* ogq = (const uint4*)og;
    #pragma unroll
    for (int i = 0; i < 4; ++i) { int idx = tid + 128 * i; if (idx < OG_U4) dstq[idx] = ogq[idx]; }
}

// ================= unified pipelined launch (R14/R16 structure) =================
// launch s: [l0-rec(s) 512] [l1-rec(s-2) 256] [l0-gemm(s+1) 4096] [l1-gemm(s-1) 2048]
#define NB_L0REC 512
#define NB_L1REC 256
#define NB_L0GEM (BATCH * 2 * NTG)
#define NB_L1GEM (BATCH * NTG)
#define NB_ALL   (NB_L0REC + NB_L1REC + NB_L0GEM + NB_L1GEM)

__global__ __launch_bounds__(128, 1) void combo_all(
    const float* __restrict__ x,
    const float* __restrict__ w_ih_f, const float* __restrict__ b_ih_f, const float* __restrict__ b_hh_f,
    const float* __restrict__ w_ih_b, const float* __restrict__ b_ih_b, const float* __restrict__ b_hh_b,
    const float* __restrict__ w_hh_f, const float* __restrict__ w_hh_b,
    const float* __restrict__ w_ih_1, const float* __restrict__ b_ih_1, const float* __restrict__ b_hh_1,
    const float* __restrict__ w_hh_1,
    __half* __restrict__ xgf0, __half* __restrict__ xgf1,
    __half* __restrict__ xgb0, __half* __restrict__ xgb1,
    __half* __restrict__ xg1a, __half* __restrict__ xg1b,
    __half* __restrict__ h0,
    float* __restrict__ stH0, float* __restrict__ stC0,
    float* __restrict__ stH1, float* __restrict__ stC1,
    int s)
{
    __shared__ __align__(16) unsigned xs[TG * 28];
    __shared__ __align__(16) __half   og[TG * G4];
    const int bid = blockIdx.x;
    if (bid < NB_L0REC) {
        if (threadIdx.x >= 64 || s > NSEG - 1) return;
        const int b = bid & (BATCH - 1);
        const int dir = bid >> 8;
        const __half* xr = dir ? ((s & 1) ? xgb1 : xgb0) : ((s & 1) ? xgf1 : xgf0);
        rec_block<true>(xr, dir ? w_hh_b : w_hh_f, h0, stH0, stC0,
                        b, dir, dir ? (NSEG - 1 - s) : s, s == 0);
    } else if (bid < NB_L0REC + NB_L1REC) {
        if (threadIdx.x >= 64 || s < 2 || s - 2 > NSEG - 1) return;
        const int b = bid - NB_L0REC;
        const __half* xr = ((s - 2) & 1) ? xg1b : xg1a;
        rec_block<false>(xr, w_hh_1, nullptr, stH1, stC1, b, 0, 0, s == 2);
    } else if (bid < NB_L0REC + NB_L1REC + NB_L0GEM) {
        if (s + 1 > NSEG - 1) return;
        const int idx = bid - (NB_L0REC + NB_L1REC);
        const int b = idx & (BATCH - 1);
        const int r = idx >> 8;                 // 0..2*NTG-1
        const int by = r & (NTG - 1);
        const int dir = r >> 3;                 // NTG == 8
        __half* dst = dir ? (((s + 1) & 1) ? xgb1 : xgb0) : (((s + 1) & 1) ? xgf1 : xgf0);
        gemm_l0_block((float*)xs, og, x,
                      dir ? w_ih_b : w_ih_f, dir ? b_ih_b : b_ih_f, dir ? b_hh_b : b_hh_f,
                      dst, b, by, dir, dir ? (NSEG - 2 - s) : (s + 1));
    } else {
        if (s < 1 || s - 1 > NSEG - 1) return;
        const int idx = bid - (NB_L0REC + NB_L1REC + NB_L0GEM);
        const int b = idx & (BATCH - 1);
        const int by = idx >> 8;                // 0..NTG-1
        __half* dst = ((s - 1) & 1) ? xg1b : xg1a;
        gemm_l1_block(xs, og, h0, w_ih_1, b_ih_1, b_hh_1, dst, b, by, s - 1);
    }
}

// prologue gemm-only launch (l0 seg0 fwd / seg15 bwd)
__global__ __launch_bounds__(128) void gemm_l0_pro(
    const float* __restrict__ x,
    const float* __restrict__ w_ih_f, const float* __restrict__ b_ih_f, const float* __restrict__ b_hh_f,
    const float* __restrict__ w_ih_b, const float* __restrict__ b_ih_b, const float* __restrict__ b_hh_b,
    __half* __restrict__ xgf, __half* __restrict__ xgb)
{
    __shared__ __align__(16) unsigned xs[TG * 28];
    __shared__ __align__(16) __half   og[TG * G4];
    const int dir = blockIdx.z;
    gemm_l0_block((float*)xs, og, x,
                  dir ? w_ih_b : w_ih_f, dir ? b_ih_b : b_ih_f, dir ? b_hh_b : b_hh_f,
                  dir ? xgb : xgf, blockIdx.x, blockIdx.y, dir, dir ? (NSEG - 1) : 0);
}

// ================= Layer 1 backward (1 step from zero state) + FC head =================
__global__ __launch_bounds__(128) void final_kernel(
    const __half* __restrict__ h0,
    const float* __restrict__ stH1,
    const float* __restrict__ w_ih1b,
    const float* __restrict__ b_ih1b, const float* __restrict__ b_hh1b,
    const float* __restrict__ fc2_w, const float* __restrict__ fc2_b,
    float* __restrict__ out)
{
    const int b   = blockIdx.x;
    const int tid = threadIdx.x;

    __shared__ float inb[2 * HID];
    __shared__ float act[G4];
    __shared__ float hb[HID];

    if (tid < HID) {
        const __half2* rr = (const __half2*)(h0 + ((size_t)b * T_LEN + (T_LEN - 1)) * (2 * HID));
        float2 v = __half22float2(rr[tid]);
        inb[2 * tid] = v.x; inb[2 * tid + 1] = v.y;
    }
    __syncthreads();

    if (tid < G4) {
        float g = b_ih1b[tid] + b_hh1b[tid];
        #pragma unroll
        for (int kk = 0; kk < 2 * HID; ++kk) g += w_ih1b[tid * (2 * HID) + kk] * inb[kk];
        act[tid] = (tid >= 2 * HID && tid < 3 * HID) ? tanhx_(g) : sigm_(g);
    }
    __syncthreads();

    if (tid < HID) {
        float c = act[tid] * act[2 * HID + tid];   // c0 = 0
        hb[tid] = act[3 * HID + tid] * tanhx_(c);
    }
    __syncthreads();

    if (tid == 0) {
        float s = fc2_b[0];
        #pragma unroll
        for (int kk = 0; kk < HID; ++kk) s += fmaxf(stH1[b * 32 + kk], 0.0f) * fc2_w[kk];
        #pragma unroll
        for (int kk = 0; kk < HID; ++kk) s += fmaxf(hb[kk], 0.0f) * fc2_w[HID + kk];
        s = fmaxf(s, 0.0f);
        out[b] = 1.0f / (1.0f + __expf(-s));
    }
}

extern "C" void kernel_launch(void* const* d_in, const int* in_sizes, int n_in,
                              void* d_out, int out_size, void* d_ws, size_t ws_size,
                              hipStream_t stream)
{
    const float* x        = (const float*)d_in[0];
    const float* w_ih_l0f = (const float*)d_in[1];
    const float* w_hh_l0f = (const float*)d_in[2];
    const float* b_ih_l0f = (const float*)d_in[3];
    const float* b_hh_l0f = (const float*)d_in[4];
    const float* w_ih_l0b = (const float*)d_in[5];
    const float* w_hh_l0b = (const float*)d_in[6];
    const float* b_ih_l0b = (const float*)d_in[7];
    const float* b_hh_l0b = (const float*)d_in[8];
    const float* w_ih_l1f = (const float*)d_in[9];
    const float* w_hh_l1f = (const float*)d_in[10];
    const float* b_ih_l1f = (const float*)d_in[11];
    const float* b_hh_l1f = (const float*)d_in[12];
    const float* w_ih_l1b = (const float*)d_in[13];
    const float* b_ih_l1b = (const float*)d_in[15];
    const float* b_hh_l1b = (const float*)d_in[16];
    const float* fc2_w    = (const float*)d_in[17];
    const float* fc2_b    = (const float*)d_in[18];
    float* out = (float*)d_out;

    // ---- workspace layout (~184 MB) ----
    const size_t H0B  = (size_t)BATCH * T_LEN * 2 * HID * sizeof(__half);   // 104,857,600
    const size_t XSEG = (size_t)BATCH * SEG_T * G4 * sizeof(__half);        // 13,107,200
    const size_t PAD  = 4096;
    char* p = (char*)d_ws;
    __half* h0   = (__half*)p;  p += H0B;
    __half* xgf0 = (__half*)p;  p += XSEG + PAD;
    __half* xgf1 = (__half*)p;  p += XSEG + PAD;
    __half* xgb0 = (__half*)p;  p += XSEG + PAD;
    __half* xgb1 = (__half*)p;  p += XSEG + PAD;
    __half* xg1a = (__half*)p;  p += XSEG + PAD;
    __half* xg1b = (__half*)p;  p += XSEG + PAD;
    float* stH0 = (float*)p;    p += 2 * BATCH * 32 * sizeof(float);
    float* stC0 = (float*)p;    p += 2 * BATCH * 32 * sizeof(float);
    float* stH1 = (float*)p;    p += BATCH * 32 * sizeof(float);
    float* stC1 = (float*)p;

    gemm_l0_pro<<<dim3(BATCH, NTG, 2), 128, 0, stream>>>(
        x, w_ih_l0f, b_ih_l0f, b_hh_l0f, w_ih_l0b, b_ih_l0b, b_hh_l0b, xgf0, xgb0);

    for (int s = 0; s <= NSEG + 1; ++s) {
        combo_all<<<NB_ALL, 128, 0, stream>>>(
            x, w_ih_l0f, b_ih_l0f, b_hh_l0f, w_ih_l0b, b_ih_l0b, b_hh_l0b,
            w_hh_l0f, w_hh_l0b,
            w_ih_l1f, b_ih_l1f, b_hh_l1f, w_hh_l1f,
            xgf0, xgf1, xgb0, xgb1, xg1a, xg1b,
            h0, stH0, stC0, stH1, stC1, s);
    }

    final_kernel<<<BATCH, 128, 0, stream>>>(
        h0, stH1, w_ih_l1b, b_ih_l1b, b_hh_l1b, fc2_w, fc2_b, out);
}

// Round 18
// 1545.787 us; speedup vs baseline: 1.2882x; 1.2882x over previous
//
#include <hip/hip_runtime.h>
#include <hip/hip_fp16.h>

#define T_LEN 4096
#define BATCH 256
#define HID   25
#define G4    100
#define NSEG  16
#define SEG_T (T_LEN / NSEG)   // 256
#define TG    32
#define NTG   (SEG_T / TG)     // 8

#define LOG2E  1.4426950408889634f
#define LOG2E2 2.8853900817779268f

#define DEV __device__ __forceinline__

#define REP13(M) M(0) M(1) M(2) M(3) M(4) M(5) M(6) M(7) M(8) M(9) M(10) M(11) M(12)

DEV float rcpf_(float x){
#if __has_builtin(__builtin_amdgcn_rcpf)
    return __builtin_amdgcn_rcpf(x);
#else
    return 1.0f / x;
#endif
}
DEV unsigned readlane_u(unsigned v, int j){
#if __has_builtin(__builtin_amdgcn_readlane)
    return (unsigned)__builtin_amdgcn_readlane((int)v, j);
#else
    return (unsigned)__shfl((int)v, j);
#endif
}
DEV unsigned pkrtz_(float a, float b){
#if __has_builtin(__builtin_amdgcn_cvt_pkrtz)
    return __builtin_bit_cast(unsigned, __builtin_amdgcn_cvt_pkrtz(a, b));
#else
    __half2 h = __floats2half2_rn(a, b);
    return __builtin_bit_cast(unsigned, h);
#endif
}
DEV float dot2acc(unsigned w, unsigned xv, float acc){
#if __has_builtin(__builtin_amdgcn_fdot2)
    typedef _Float16 h2v __attribute__((ext_vector_type(2)));
    return __builtin_amdgcn_fdot2(__builtin_bit_cast(h2v, w),
                                  __builtin_bit_cast(h2v, xv), acc, false);
#else
    __half2 a = __builtin_bit_cast(__half2, w), b2 = __builtin_bit_cast(__half2, xv);
    float2 fa = __half22float2(a), fb = __half22float2(b2);
    return acc + fa.x * fb.x + fa.y * fb.y;
#endif
}
DEV float sigm_(float x){ return 1.0f - rcpf_(__expf(x) + 1.0f); }
DEV float tanhx_(float x){ return 1.0f - 2.0f * rcpf_(__expf(2.0f * x) + 1.0f); }

// row0-broadcast: every lane receives the value held by lane (lane&31) of the LOWER half.
// Verified on HW (rounds 4-17, absmax 0).
DEV float bcast_row0(float v){
#if __has_builtin(__builtin_amdgcn_permlane32_swap)
    auto r = __builtin_amdgcn_permlane32_swap(__float_as_int(v), __float_as_int(v), false, false);
    return __int_as_float(r[0]);
#else
    return __shfl(v, (int)(threadIdx.x & 31), 64);
#endif
}

// ============ recurrence: R7 chain + DPP pair-packing of h (cuts ~35 VALU ops/step) ============
// lane k (<32): gates (i,f); lane 32+k: gates (g,o). Cell update lane-local on upper half.
// h-broadcast: lane 32+2m packs (h_{2m}, h_{2m+1}) via shfl_down+pkrtz; 13 readlane of the
// PACKED dwords replace 25 readlane + 13 pkrtz. Odd tail (m=12) safe: weight .y slot is 0.
template<bool STORE>
DEV void rec_block(const __half* __restrict__ xg,
                   const float* __restrict__ w_hh,
                   __half* __restrict__ h0out,
                   float* __restrict__ stH, float* __restrict__ stC,
                   int b, int dir, int seg, int first)
{
    const int lane = threadIdx.x;          // caller guarantees < 64
    const int k    = ((lane & 31) < HID) ? (lane & 31) : 0;
    const bool up  = lane >= 32;
    const int rowA = up ? (2 * HID + k) : k;          // g : i
    const int rowB = up ? (3 * HID + k) : (HID + k);  // o : f
    const float scA  = up ? LOG2E2 : LOG2E;
    const float coef = up ? 2.0f : 1.0f;

#define DECLW(m) unsigned wA##m, wB##m;
    REP13(DECLW)
#undef DECLW
#define LOADW(m) { \
    const bool tl = (2 * m + 1 < HID); \
    float a0 = w_hh[rowA * HID + 2 * m] * scA; \
    float a1 = tl ? w_hh[rowA * HID + 2 * m + 1] * scA : 0.0f; \
    float b0 = w_hh[rowB * HID + 2 * m] * LOG2E; \
    float b1 = tl ? w_hh[rowB * HID + 2 * m + 1] * LOG2E : 0.0f; \
    wA##m = pkrtz_(a0, a1); \
    wB##m = pkrtz_(b0, b1); }
    REP13(LOADW)
#undef LOADW

    const int sidx = (dir * BATCH + b) * 32 + k;
    float h = 0.0f, cst = 0.0f;
    if (!first) { h = stH[sidx]; cst = stC[sidx]; }

    const unsigned* src = (const unsigned*)xg + (size_t)b * SEG_T * (G4 / 2)
                        + (k * 2 + (up ? 1 : 0));
    unsigned pf[8];
    #pragma unroll
    for (int s = 0; s < 8; ++s) pf[s] = src[s * (G4 / 2)];
    const unsigned* pnext = src + 8 * (G4 / 2);

    __half* sptr = nullptr;
    long long sstride = 0;
    if (STORE) {
        const int tstart = dir ? (seg * SEG_T + SEG_T - 1) : (seg * SEG_T);
        sptr = h0out + ((size_t)b * T_LEN + tstart) * (2 * HID) + dir * HID + k;
        sstride = dir ? -(long long)(2 * HID) : (long long)(2 * HID);
    }
    const bool store_lane = up && ((lane & 31) < HID);

    for (int tb = 0; tb < SEG_T; tb += 8) {
        // pin the 26 packed weights live across the back-edge
        asm volatile("" :
            "+v"(wA0), "+v"(wA1), "+v"(wA2), "+v"(wA3), "+v"(wA4), "+v"(wA5),
            "+v"(wA6), "+v"(wA7), "+v"(wA8), "+v"(wA9), "+v"(wA10), "+v"(wA11), "+v"(wA12),
            "+v"(wB0), "+v"(wB1), "+v"(wB2), "+v"(wB3), "+v"(wB4), "+v"(wB5),
            "+v"(wB6), "+v"(wB7), "+v"(wB8), "+v"(wB9), "+v"(wB10), "+v"(wB11), "+v"(wB12));
        #pragma unroll
        for (int s = 0; s < 8; ++s) {
            const unsigned cur = pf[s];
            pf[s] = pnext[s * (G4 / 2)];             // rolling prefetch t+8 (pad absorbs tail)
            const __half2 hx = __builtin_bit_cast(__half2, cur);
            const float2 xv = __half22float2(hx);
            // pack h pairs in-lane: lane 32+2m holds pack(h_{2m}, h_{2m+1})
            float hsh = __shfl_down(h, 1);
            unsigned hpk = pkrtz_(h, hsh);
#define HP(m) unsigned hp##m = readlane_u(hpk, 32 + 2 * m);
            REP13(HP)
#undef HP
            float aA0 = xv.x, aA1 = 0.0f, aB0 = xv.y, aB1 = 0.0f;
#define DT(m) { if ((m) & 1) { aA1 = dot2acc(wA##m, hp##m, aA1); aB1 = dot2acc(wB##m, hp##m, aB1); } \
                else         { aA0 = dot2acc(wA##m, hp##m, aA0); aB0 = dot2acc(wB##m, hp##m, aB0); } }
            REP13(DT)
#undef DT
            const float aA = aA0 + aA1;
            const float aB = aB0 + aB1;
            float e0 = __builtin_exp2f(aA);
            float e1 = __builtin_exp2f(aB);
            float u0 = 1.0f - coef * rcpf_(e0 + 1.0f);   // lower: sig(i); upper: tanh(g)
            float u1 = 1.0f - rcpf_(e1 + 1.0f);          // lower: sig(f); upper: sig(o)
            float si = bcast_row0(u0);
            float sf = bcast_row0(u1);
            cst = sf * cst + si * u0;                    // upper: f*c + i*tanh(g)
            float tc = 1.0f - 2.0f * rcpf_(__builtin_exp2f(LOG2E2 * cst) + 1.0f);
            h = u1 * tc;                                 // upper: sig(o)*tanh(c)
            if (STORE) {
                if (store_lane) *sptr = __float2half(h);
                sptr += sstride;
            }
        }
        pnext += 8 * (G4 / 2);
    }
    if (store_lane) { stH[sidx] = h; stC[sidx] = cst; }
}

// ================= xg GEMM blocks =================
#define OG_U4 ((TG * G4) / 8)   // 400 uint4

// l0: f32 math, f32 LDS rows padded to 28 -> 6 x ds_read_b128 + 1 b32 per t.
DEV void gemm_l0_block(float* xs, __half* og,
                       const float* __restrict__ x,
                       const float* __restrict__ w_ih, const float* __restrict__ b_ih,
                       const float* __restrict__ b_hh,
                       __half* __restrict__ xgdst, int b, int by, int dir, int seg)
{
    const int tid = threadIdx.x;
    const int t0 = seg * SEG_T + by * TG;
    const float* src = x + ((size_t)b * T_LEN + t0) * HID;
    #pragma unroll
    for (int i = 0; i < 7; ++i) {
        int idx = tid + 128 * i;
        if (idx < TG * HID) {
            int r = idx / HID, d = idx - r * HID;
            int row = dir ? (TG - 1 - r) : r;
            xs[row * 28 + d] = src[idx];
        }
    }
    __syncthreads();
    if (tid < G4) {
        const int g = tid;
        const float sc = (g >= 2 * HID && g < 3 * HID) ? LOG2E2 : LOG2E;
        float w[HID];
        #pragma unroll
        for (int j = 0; j < HID; ++j) w[j] = w_ih[g * HID + j] * sc;
        const float bias = (b_ih[g] + b_hh[g]) * sc;
        const int pos = (g % HID) * 4 + (g / HID);
        for (int t = 0; t < TG; ++t) {
            const float4* xq = (const float4*)(xs + t * 28);
            float4 q0 = xq[0], q1 = xq[1], q2 = xq[2], q3 = xq[3], q4 = xq[4], q5 = xq[5];
            float e24 = xs[t * 28 + 24];
            float a0 = bias, a1 = 0.f, a2 = 0.f, a3 = 0.f;
            a0 = fmaf(w[0],  q0.x, a0);  a1 = fmaf(w[1],  q0.y, a1);
            a2 = fmaf(w[2],  q0.z, a2);  a3 = fmaf(w[3],  q0.w, a3);
            a0 = fmaf(w[4],  q1.x, a0);  a1 = fmaf(w[5],  q1.y, a1);
            a2 = fmaf(w[6],  q1.z, a2);  a3 = fmaf(w[7],  q1.w, a3);
            a0 = fmaf(w[8],  q2.x, a0);  a1 = fmaf(w[9],  q2.y, a1);
            a2 = fmaf(w[10], q2.z, a2);  a3 = fmaf(w[11], q2.w, a3);
            a0 = fmaf(w[12], q3.x, a0);  a1 = fmaf(w[13], q3.y, a1);
            a2 = fmaf(w[14], q3.z, a2);  a3 = fmaf(w[15], q3.w, a3);
            a0 = fmaf(w[16], q4.x, a0);  a1 = fmaf(w[17], q4.y, a1);
            a2 = fmaf(w[18], q4.z, a2);  a3 = fmaf(w[19], q4.w, a3);
            a0 = fmaf(w[20], q5.x, a0);  a1 = fmaf(w[21], q5.y, a1);
            a2 = fmaf(w[22], q5.z, a2);  a3 = fmaf(w[23], q5.w, a3);
            a0 = fmaf(w[24], e24, a0);
            og[t * G4 + pos] = __float2half((a0 + a1) + (a2 + a3));
        }
    }
    __syncthreads();
    const int rowbase = (dir ? (NTG - 1 - by) : by) * TG;
    uint4* dstq = (uint4*)((unsigned*)xgdst + ((size_t)b * SEG_T + rowbase) * (G4 / 2));
    const uint4* ogq = (const uint4*)og;
    #pragma unroll
    for (int i = 0; i < 4; ++i) { int idx = tid + 128 * i; if (idx < OG_U4) dstq[idx] = ogq[idx]; }
}

// l1: fp16 inputs (h0 already fp16); rows padded to 28 dwords; RNE weight packing (R11-validated).
DEV void gemm_l1_block(unsigned* xs, __half* og,
                       const __half* __restrict__ h0,
                       const float* __restrict__ w_ih, const float* __restrict__ b_ih,
                       const float* __restrict__ b_hh,
                       __half* __restrict__ xgdst, int b, int by, int seg)
{
    const int tid = threadIdx.x;
    const int t0 = seg * SEG_T + by * TG;
    const unsigned* src = (const unsigned*)h0 + ((size_t)b * T_LEN + t0) * HID;
    #pragma unroll
    for (int i = 0; i < 7; ++i) {
        int idx = tid + 128 * i;
        if (idx < TG * HID) {
            int r = idx / HID, d = idx - r * HID;
            xs[r * 28 + d] = src[idx];
        }
    }
    __syncthreads();
    if (tid < G4) {
        const int g = tid;
        const float sc = (g >= 2 * HID && g < 3 * HID) ? LOG2E2 : LOG2E;
        unsigned wp[HID];
        #pragma unroll
        for (int j = 0; j < HID; ++j) {
            __half2 hw = __floats2half2_rn(w_ih[g * (2 * HID) + 2 * j] * sc,
                                           w_ih[g * (2 * HID) + 2 * j + 1] * sc);
            wp[j] = __builtin_bit_cast(unsigned, hw);
        }
        const float bias = (b_ih[g] + b_hh[g]) * sc;
        const int pos = (g % HID) * 4 + (g / HID);
        for (int t = 0; t < TG; ++t) {
            const uint4* xq = (const uint4*)(xs + t * 28);
            uint4 q0 = xq[0], q1 = xq[1], q2 = xq[2], q3 = xq[3], q4 = xq[4], q5 = xq[5];
            unsigned d24 = xs[t * 28 + 24];
            float a0 = bias, a1 = 0.f, a2 = 0.f, a3 = 0.f;
            a0 = dot2acc(wp[0], q0.x, a0);   a1 = dot2acc(wp[1], q0.y, a1);
            a2 = dot2acc(wp[2], q0.z, a2);   a3 = dot2acc(wp[3], q0.w, a3);
            a0 = dot2acc(wp[4], q1.x, a0);   a1 = dot2acc(wp[5], q1.y, a1);
            a2 = dot2acc(wp[6], q1.z, a2);   a3 = dot2acc(wp[7], q1.w, a3);
            a0 = dot2acc(wp[8], q2.x, a0);   a1 = dot2acc(wp[9], q2.y, a1);
            a2 = dot2acc(wp[10], q2.z, a2);  a3 = dot2acc(wp[11], q2.w, a3);
            a0 = dot2acc(wp[12], q3.x, a0);  a1 = dot2acc(wp[13], q3.y, a1);
            a2 = dot2acc(wp[14], q3.z, a2);  a3 = dot2acc(wp[15], q3.w, a3);
            a0 = dot2acc(wp[16], q4.x, a0);  a1 = dot2acc(wp[17], q4.y, a1);
            a2 = dot2acc(wp[18], q4.z, a2);  a3 = dot2acc(wp[19], q4.w, a3);
            a0 = dot2acc(wp[20], q5.x, a0);  a1 = dot2acc(wp[21], q5.y, a1);
            a2 = dot2acc(wp[22], q5.z, a2);  a3 = dot2acc(wp[23], q5.w, a3);
            a0 = dot2acc(wp[24], d24, a0);
            og[t * G4 + pos] = __float2half((a0 + a1) + (a2 + a3));
        }
    }
    __syncthreads();
    uint4* dstq = (uint4*)((unsigned*)xgdst + ((size_t)b * SEG_T + (size_t)by * TG) * (G4 / 2));
    const uint4* ogq = (const uint4*)og;
    #pragma unroll
    for (int i = 0; i < 4; ++i) { int idx = tid + 128 * i; if (idx < OG_U4) dstq[idx] = ogq[idx]; }
}

// ================= unified pipelined launch =================
#define NB_L0REC 512
#define NB_L1REC 256
#define NB_L0GEM (BATCH * 2 * NTG)
#define NB_L1GEM (BATCH * NTG)
#define NB_ALL   (NB_L0REC + NB_L1REC + NB_L0GEM + NB_L1GEM)

__global__ __launch_bounds__(128, 1) void combo_all(
    const float* __restrict__ x,
    const float* __restrict__ w_ih_f, const float* __restrict__ b_ih_f, const float* __restrict__ b_hh_f,
    const float* __restrict__ w_ih_b, const float* __restrict__ b_ih_b, const float* __restrict__ b_hh_b,
    const float* __restrict__ w_hh_f, const float* __restrict__ w_hh_b,
    const float* __restrict__ w_ih_1, const float* __restrict__ b_ih_1, const float* __restrict__ b_hh_1,
    const float* __restrict__ w_hh_1,
    __half* __restrict__ xgf0, __half* __restrict__ xgf1,
    __half* __restrict__ xgb0, __half* __restrict__ xgb1,
    __half* __restrict__ xg1a, __half* __restrict__ xg1b,
    __half* __restrict__ h0,
    float* __restrict__ stH0, float* __restrict__ stC0,
    float* __restrict__ stH1, float* __restrict__ stC1,
    int s)
{
    __shared__ __align__(16) unsigned xs[TG * 28];
    __shared__ __align__(16) __half   og[TG * G4];
    const int bid = blockIdx.x;
    if (bid < NB_L0REC) {
        if (threadIdx.x >= 64 || s > NSEG - 1) return;
        const int b = bid & (BATCH - 1);
        const int dir = bid >> 8;
        const __half* xr = dir ? ((s & 1) ? xgb1 : xgb0) : ((s & 1) ? xgf1 : xgf0);
        rec_block<true>(xr, dir ? w_hh_b : w_hh_f, h0, stH0, stC0,
                        b, dir, dir ? (NSEG - 1 - s) : s, s == 0);
    } else if (bid < NB_L0REC + NB_L1REC) {
        if (threadIdx.x >= 64 || s < 2 || s - 2 > NSEG - 1) return;
        const int b = bid - NB_L0REC;
        const __half* xr = ((s - 2) & 1) ? xg1b : xg1a;
        rec_block<false>(xr, w_hh_1, nullptr, stH1, stC1, b, 0, 0, s == 2);
    } else if (bid < NB_L0REC + NB_L1REC + NB_L0GEM) {
        if (s + 1 > NSEG - 1) return;
        const int idx = bid - (NB_L0REC + NB_L1REC);
        const int b = idx & (BATCH - 1);
        const int r = idx >> 8;                 // 0..2*NTG-1
        const int by = r & (NTG - 1);
        const int dir = r >> 3;                 // NTG == 8
        __half* dst = dir ? (((s + 1) & 1) ? xgb1 : xgb0) : (((s + 1) & 1) ? xgf1 : xgf0);
        gemm_l0_block((float*)xs, og, x,
                      dir ? w_ih_b : w_ih_f, dir ? b_ih_b : b_ih_f, dir ? b_hh_b : b_hh_f,
                      dst, b, by, dir, dir ? (NSEG - 2 - s) : (s + 1));
    } else {
        if (s < 1 || s - 1 > NSEG - 1) return;
        const int idx = bid - (NB_L0REC + NB_L1REC + NB_L0GEM);
        const int b = idx & (BATCH - 1);
        const int by = idx >> 8;                // 0..NTG-1
        __half* dst = ((s - 1) & 1) ? xg1b : xg1a;
        gemm_l1_block(xs, og, h0, w_ih_1, b_ih_1, b_hh_1, dst, b, by, s - 1);
    }
}

// prologue gemm-only launch (l0 seg0 fwd / seg15 bwd)
__global__ __launch_bounds__(128) void gemm_l0_pro(
    const float* __restrict__ x,
    const float* __restrict__ w_ih_f, const float* __restrict__ b_ih_f, const float* __restrict__ b_hh_f,
    const float* __restrict__ w_ih_b, const float* __restrict__ b_ih_b, const float* __restrict__ b_hh_b,
    __half* __restrict__ xgf, __half* __restrict__ xgb)
{
    __shared__ __align__(16) unsigned xs[TG * 28];
    __shared__ __align__(16) __half   og[TG * G4];
    const int dir = blockIdx.z;
    gemm_l0_block((float*)xs, og, x,
                  dir ? w_ih_b : w_ih_f, dir ? b_ih_b : b_ih_f, dir ? b_hh_b : b_hh_f,
                  dir ? xgb : xgf, blockIdx.x, blockIdx.y, dir, dir ? (NSEG - 1) : 0);
}

// ================= Layer 1 backward (1 step from zero state) + FC head =================
__global__ __launch_bounds__(128) void final_kernel(
    const __half* __restrict__ h0,
    const float* __restrict__ stH1,
    const float* __restrict__ w_ih1b,
    const float* __restrict__ b_ih1b, const float* __restrict__ b_hh1b,
    const float* __restrict__ fc2_w, const float* __restrict__ fc2_b,
    float* __restrict__ out)
{
    const int b   = blockIdx.x;
    const int tid = threadIdx.x;

    __shared__ float inb[2 * HID];
    __shared__ float act[G4];
    __shared__ float hb[HID];

    if (tid < HID) {
        const __half2* rr = (const __half2*)(h0 + ((size_t)b * T_LEN + (T_LEN - 1)) * (2 * HID));
        float2 v = __half22float2(rr[tid]);
        inb[2 * tid] = v.x; inb[2 * tid + 1] = v.y;
    }
    __syncthreads();

    if (tid < G4) {
        float g = b_ih1b[tid] + b_hh1b[tid];
        #pragma unroll
        for (int kk = 0; kk < 2 * HID; ++kk) g += w_ih1b[tid * (2 * HID) + kk] * inb[kk];
        act[tid] = (tid >= 2 * HID && tid < 3 * HID) ? tanhx_(g) : sigm_(g);
    }
    __syncthreads();

    if (tid < HID) {
        float c = act[tid] * act[2 * HID + tid];   // c0 = 0
        hb[tid] = act[3 * HID + tid] * tanhx_(c);
    }
    __syncthreads();

    if (tid == 0) {
        float s = fc2_b[0];
        #pragma unroll
        for (int kk = 0; kk < HID; ++kk) s += fmaxf(stH1[b * 32 + kk], 0.0f) * fc2_w[kk];
        #pragma unroll
        for (int kk = 0; kk < HID; ++kk) s += fmaxf(hb[kk], 0.0f) * fc2_w[HID + kk];
        s = fmaxf(s, 0.0f);
        out[b] = 1.0f / (1.0f + __expf(-s));
    }
}

extern "C" void kernel_launch(void* const* d_in, const int* in_sizes, int n_in,
                              void* d_out, int out_size, void* d_ws, size_t ws_size,
                              hipStream_t stream)
{
    const float* x        = (const float*)d_in[0];
    const float* w_ih_l0f = (const float*)d_in[1];
    const float* w_hh_l0f = (const float*)d_in[2];
    const float* b_ih_l0f = (const float*)d_in[3];
    const float* b_hh_l0f = (const float*)d_in[4];
    const float* w_ih_l0b = (const float*)d_in[5];
    const float* w_hh_l0b = (const float*)d_in[6];
    const float* b_ih_l0b = (const float*)d_in[7];
    const float* b_hh_l0b = (const float*)d_in[8];
    const float* w_ih_l1f = (const float*)d_in[9];
    const float* w_hh_l1f = (const float*)d_in[10];
    const float* b_ih_l1f = (const float*)d_in[11];
    const float* b_hh_l1f = (const float*)d_in[12];
    const float* w_ih_l1b = (const float*)d_in[13];
    const float* b_ih_l1b = (const float*)d_in[15];
    const float* b_hh_l1b = (const float*)d_in[16];
    const float* fc2_w    = (const float*)d_in[17];
    const float* fc2_b    = (const float*)d_in[18];
    float* out = (float*)d_out;

    // ---- workspace layout (~184 MB) ----
    const size_t H0B  = (size_t)BATCH * T_LEN * 2 * HID * sizeof(__half);   // 104,857,600
    const size_t XSEG = (size_t)BATCH * SEG_T * G4 * sizeof(__half);        // 13,107,200
    const size_t PAD  = 4096;
    char* p = (char*)d_ws;
    __half* h0   = (__half*)p;  p += H0B;
    __half* xgf0 = (__half*)p;  p += XSEG + PAD;
    __half* xgf1 = (__half*)p;  p += XSEG + PAD;
    __half* xgb0 = (__half*)p;  p += XSEG + PAD;
    __half* xgb1 = (__half*)p;  p += XSEG + PAD;
    __half* xg1a = (__half*)p;  p += XSEG + PAD;
    __half* xg1b = (__half*)p;  p += XSEG + PAD;
    float* stH0 = (float*)p;    p += 2 * BATCH * 32 * sizeof(float);
    float* stC0 = (float*)p;    p += 2 * BATCH * 32 * sizeof(float);
    float* stH1 = (float*)p;    p += BATCH * 32 * sizeof(float);
    float* stC1 = (float*)p;

    gemm_l0_pro<<<dim3(BATCH, NTG, 2), 128, 0, stream>>>(
        x, w_ih_l0f, b_ih_l0f, b_hh_l0f, w_ih_l0b, b_ih_l0b, b_hh_l0b, xgf0, xgb0);

    for (int s = 0; s <= NSEG + 1; ++s) {
        combo_all<<<NB_ALL, 128, 0, stream>>>(
            x, w_ih_l0f, b_ih_l0f, b_hh_l0f, w_ih_l0b, b_ih_l0b, b_hh_l0b,
            w_hh_l0f, w_hh_l0b,
            w_ih_l1f, b_ih_l1f, b_hh_l1f, w_hh_l1f,
            xgf0, xgf1, xgb0, xgb1, xg1a, xg1b,
            h0, stH0, stC0, stH1, stC1, s);
    }

    final_kernel<<<BATCH, 128, 0, stream>>>(
        h0, stH1, w_ih_l1b, b_ih_l1b, b_hh_l1b, fc2_w, fc2_b, out);
}